// Round 5
// baseline (181.865 us; speedup 1.0000x reference)
//
#include <hip/hip_runtime.h>
#include <math.h>

typedef float v4f __attribute__((ext_vector_type(4)));
typedef short bf16x8 __attribute__((ext_vector_type(8)));

#define AS1 __attribute__((address_space(1)))
#define AS3 __attribute__((address_space(3)))

static constexpr int Bn = 8192;   // batch
static constexpr int Hn = 768;    // hidden
static constexpr float invB = 1.0f / 8192.0f;

__device__ __forceinline__ short f32_to_bf16(float x) {
    union { float f; unsigned u; } v; v.f = x;
    unsigned r = (v.u + 0x7FFFu + ((v.u >> 16) & 1u)) >> 16;
    return (short)r;
}

// tanh(x) = 1 - 2/(exp(2x)+1)
__device__ __forceinline__ float fast_tanh(float x) {
    float xc = fminf(fmaxf(x, -15.0f), 15.0f);
    float e = __expf(2.0f * xc);
    float r = __builtin_amdgcn_rcpf(e + 1.0f);
    return 1.0f - 2.0f * r;
}

// ---------------- fused prep: zero accumulators + fp32->bf16 all 5 tensors ----------------
__global__ void prep_kernel(const float* __restrict__ A,
                            const float* __restrict__ W1m, const float* __restrict__ W2m,
                            const float* __restrict__ W1v, const float* __restrict__ W2v,
                            short* __restrict__ A_bf,
                            short* __restrict__ W1m_bf, short* __restrict__ W2m_bf,
                            short* __restrict__ W1v_bf, short* __restrict__ W2v_bf,
                            float* __restrict__ zbuf, int nzero) {
    const int tid = blockIdx.x * blockDim.x + threadIdx.x;
    if (tid < nzero) zbuf[tid] = 0.0f;
    constexpr int A4 = Bn * Hn / 4;
    constexpr int W4 = Hn * Hn / 4;
    const int total = A4 + 4 * W4;
    const int stride = gridDim.x * blockDim.x;
    for (int i = tid; i < total; i += stride) {
        const float* s; short* d; int j;
        if (i < A4) { s = A; d = A_bf; j = i; }
        else {
            int k = i - A4; int w = k / W4; j = k - w * W4;
            s = (w == 0) ? W1m : (w == 1) ? W2m : (w == 2) ? W1v : W2v;
            d = (w == 0) ? W1m_bf : (w == 1) ? W2m_bf : (w == 2) ? W1v_bf : W2v_bf;
        }
        float4 v = ((const float4*)s)[j];
        short4 o;
        o.x = f32_to_bf16(v.x); o.y = f32_to_bf16(v.y);
        o.z = f32_to_bf16(v.z); o.w = f32_to_bf16(v.w);
        ((short4*)d)[j] = o;
    }
}

// ---------------- LAYER 1: z-paired 128x128 tile, 16x16x32 MFMA (R2 engine) ----------------
// blockIdx.z: 0 -> m branch, 1 -> v branch. out = bf16(fast_tanh(A@W^T + b)), LDS-coalesced store.
__launch_bounds__(256, 3)
__global__ void gemm_l1(const short* __restrict__ A_g,
                        const short* __restrict__ Wm_g, const short* __restrict__ Wv_g,
                        const float* __restrict__ bm, const float* __restrict__ bv,
                        short* __restrict__ outm, short* __restrict__ outv) {
    constexpr int K = Hn;
    __shared__ __align__(16) short smem[16384];   // 32KB: As 8192 | Ws 8192; reused by epilogue
    short* As = smem;
    short* Ws = smem + 8192;

    const int z = blockIdx.z;
    const short* W = z ? Wv_g : Wm_g;
    const float* bias = z ? bv : bm;
    short* out = z ? outv : outm;

    const int t = threadIdx.x;
    const int row0 = blockIdx.x * 128;
    const int col0 = blockIdx.y * 128;
    const int w = t >> 6, lane = t & 63;
    const int wm = w >> 1, wn = w & 1;    // 2x2 waves, 64x64 each
    const int lr = lane & 15, quad = lane >> 4;

    const int rt = t >> 3;                // 0..31
    const int bsrc = (t & 7) ^ (rt & 7);  // XOR-swizzled k-block source

    const short* pA[4]; const short* pW[4];
#pragma unroll
    for (int i = 0; i < 4; ++i) {
        pA[i] = A_g + (size_t)(row0 + i * 32 + rt) * K + bsrc * 8;
        pW[i] = W + (size_t)(col0 + i * 32 + rt) * K + bsrc * 8;
    }

    v4f acc[4][4] = {};

    for (int k0 = 0; k0 < K; k0 += 64) {
#pragma unroll
        for (int i = 0; i < 4; ++i) {
            __builtin_amdgcn_global_load_lds((AS1 void*)pA[i], (AS3 void*)&As[i * 2048 + t * 8], 16, 0, 0);
            __builtin_amdgcn_global_load_lds((AS1 void*)pW[i], (AS3 void*)&Ws[i * 2048 + t * 8], 16, 0, 0);
            pA[i] += 64; pW[i] += 64;
        }
        __syncthreads();
#pragma unroll
        for (int s = 0; s < 2; ++s) {
            const int kb = s * 4 + quad;
            bf16x8 af[4], bfr[4];
#pragma unroll
            for (int mt = 0; mt < 4; ++mt) {
                int m = wm * 64 + mt * 16 + lr;
                af[mt] = *(const bf16x8*)&As[m * 64 + ((kb ^ (m & 7)) << 3)];
            }
#pragma unroll
            for (int nt = 0; nt < 4; ++nt) {
                int n = wn * 64 + nt * 16 + lr;
                bfr[nt] = *(const bf16x8*)&Ws[n * 64 + ((kb ^ (n & 7)) << 3)];
            }
#pragma unroll
            for (int mt = 0; mt < 4; ++mt)
#pragma unroll
                for (int nt = 0; nt < 4; ++nt)
                    acc[mt][nt] = __builtin_amdgcn_mfma_f32_16x16x32_bf16(af[mt], bfr[nt], acc[mt][nt], 0, 0, 0);
        }
        __syncthreads();
    }

    // ---- epilogue: tanh -> LDS (128x128 bf16 = 32KB) -> coalesced 16B/lane stores ----
#pragma unroll
    for (int nt = 0; nt < 4; ++nt) {
        const int col_l = wn * 64 + nt * 16 + lr;
        const float bc = bias[col0 + col_l];
#pragma unroll
        for (int mt = 0; mt < 4; ++mt) {
#pragma unroll
            for (int r = 0; r < 4; ++r) {
                const int row_l = wm * 64 + mt * 16 + quad * 4 + r;
                smem[row_l * 128 + col_l] = f32_to_bf16(fast_tanh(acc[mt][nt][r] + bc));
            }
        }
    }
    __syncthreads();
#pragma unroll
    for (int p = 0; p < 8; ++p) {
        const int row_l = p * 16 + (t >> 4);
        const int seg = (t & 15) * 8;
        bf16x8 v = *(const bf16x8*)&smem[row_l * 128 + seg];
        *(bf16x8*)&out[(size_t)(row0 + row_l) * Hn + col0 + seg] = v;
    }
}

// ---------------- LAYER 2: branch-paired 128x64 tile, 16x16 MFMA, CLUB epilogue + finalize ----------------
__launch_bounds__(256, 3)
__global__ void gemm_l2(const short* __restrict__ Am_g, const short* __restrict__ Av_g,
                        const short* __restrict__ Wm_g, const short* __restrict__ Wv_g,
                        const float* __restrict__ bm, const float* __restrict__ bv,
                        const float* __restrict__ mb,
                        float* __restrict__ cs, float* __restrict__ cs2,
                        float* __restrict__ siv, float* __restrict__ sivmu,
                        float* __restrict__ accum, float* __restrict__ outp) {
    constexpr int K = Hn;
    __shared__ __align__(16) short As_m[128 * 64];   // 16KB
    __shared__ __align__(16) short As_v[128 * 64];   // 16KB
    __shared__ __align__(16) short Ws_m[64 * 64];    // 8KB
    __shared__ __align__(16) short Ws_v[64 * 64];    // 8KB  (48KB total -> 3 blocks/CU)

    const int t = threadIdx.x;
    const int row0 = blockIdx.x * 128;
    const int col0 = blockIdx.y * 64;
    const int w = t >> 6, lane = t & 63;
    const int wm = w >> 1, wn = w & 1;    // wave tile: 64 rows x 32 cols per branch
    const int lr = lane & 15, quad = lane >> 4;

    const int rt = t >> 3;
    const int bsrc = (t & 7) ^ (rt & 7);

    const short* pAm[4]; const short* pAv[4]; const short* pWm[2]; const short* pWv[2];
#pragma unroll
    for (int i = 0; i < 4; ++i) {
        pAm[i] = Am_g + (size_t)(row0 + i * 32 + rt) * K + bsrc * 8;
        pAv[i] = Av_g + (size_t)(row0 + i * 32 + rt) * K + bsrc * 8;
    }
#pragma unroll
    for (int i = 0; i < 2; ++i) {
        pWm[i] = Wm_g + (size_t)(col0 + i * 32 + rt) * K + bsrc * 8;
        pWv[i] = Wv_g + (size_t)(col0 + i * 32 + rt) * K + bsrc * 8;
    }

    v4f accm[4][2] = {}, accv[4][2] = {};

    for (int k0 = 0; k0 < K; k0 += 64) {
#pragma unroll
        for (int i = 0; i < 4; ++i) {
            __builtin_amdgcn_global_load_lds((AS1 void*)pAm[i], (AS3 void*)&As_m[i * 2048 + t * 8], 16, 0, 0);
            __builtin_amdgcn_global_load_lds((AS1 void*)pAv[i], (AS3 void*)&As_v[i * 2048 + t * 8], 16, 0, 0);
            pAm[i] += 64; pAv[i] += 64;
        }
#pragma unroll
        for (int i = 0; i < 2; ++i) {
            __builtin_amdgcn_global_load_lds((AS1 void*)pWm[i], (AS3 void*)&Ws_m[i * 2048 + t * 8], 16, 0, 0);
            __builtin_amdgcn_global_load_lds((AS1 void*)pWv[i], (AS3 void*)&Ws_v[i * 2048 + t * 8], 16, 0, 0);
            pWm[i] += 64; pWv[i] += 64;
        }
        __syncthreads();
#pragma unroll
        for (int s = 0; s < 2; ++s) {
            const int kb = s * 4 + quad;
            bf16x8 am[4], av[4], bmf[2], bvf[2];
#pragma unroll
            for (int mt = 0; mt < 4; ++mt) {
                int m = wm * 64 + mt * 16 + lr;
                int off = m * 64 + ((kb ^ (m & 7)) << 3);
                am[mt] = *(const bf16x8*)&As_m[off];
                av[mt] = *(const bf16x8*)&As_v[off];
            }
#pragma unroll
            for (int nt = 0; nt < 2; ++nt) {
                int n = wn * 32 + nt * 16 + lr;
                int off = n * 64 + ((kb ^ (n & 7)) << 3);
                bmf[nt] = *(const bf16x8*)&Ws_m[off];
                bvf[nt] = *(const bf16x8*)&Ws_v[off];
            }
#pragma unroll
            for (int mt = 0; mt < 4; ++mt)
#pragma unroll
                for (int nt = 0; nt < 2; ++nt) {
                    accm[mt][nt] = __builtin_amdgcn_mfma_f32_16x16x32_bf16(am[mt], bmf[nt], accm[mt][nt], 0, 0, 0);
                    accv[mt][nt] = __builtin_amdgcn_mfma_f32_16x16x32_bf16(av[mt], bvf[nt], accv[mt][nt], 0, 0, 0);
                }
        }
        __syncthreads();
    }

    // ---------------- CLUB epilogue ----------------
    float pos = 0.f, q = 0.f;   // pos = sum iv*(mu-mb)^2 ; q = sum iv*mu^2
#pragma unroll
    for (int nt = 0; nt < 2; ++nt) {
        const int col = col0 + wn * 32 + nt * 16 + lr;
        const float bmc = bm[col], bvc = bv[col];
        float c1 = 0.f, c2 = 0.f, c3 = 0.f, c4 = 0.f;
#pragma unroll
        for (int mt = 0; mt < 4; ++mt) {
#pragma unroll
            for (int r = 0; r < 4; ++r) {
                const int row = row0 + wm * 64 + mt * 16 + quad * 4 + r;
                float mu = accm[mt][nt][r] + bmc;
                float tv = fast_tanh(accv[mt][nt][r] + bvc);
                float iv = __expf(-tv);
                float mbv = mb[(size_t)row * Hn + col];
                float d = mu - mbv;
                pos += iv * d * d;
                q   += iv * mu * mu;
                c1 += mu; c2 += mu * mu; c3 += iv; c4 += iv * mu;
            }
        }
        c1 += __shfl_xor(c1, 16); c1 += __shfl_xor(c1, 32);
        c2 += __shfl_xor(c2, 16); c2 += __shfl_xor(c2, 32);
        c3 += __shfl_xor(c3, 16); c3 += __shfl_xor(c3, 32);
        c4 += __shfl_xor(c4, 16); c4 += __shfl_xor(c4, 32);
        if (quad == 0) {
            atomicAdd(&cs[col], c1);
            atomicAdd(&cs2[col], c2);
            atomicAdd(&siv[col], c3);
            atomicAdd(&sivmu[col], c4);
        }
    }
    // block-reduce the two scalars
    for (int off = 32; off > 0; off >>= 1) {
        pos += __shfl_down(pos, off);
        q   += __shfl_down(q, off);
    }
    __shared__ float redP[4], redQ[4];
    if (lane == 0) { redP[w] = pos; redQ[w] = q; }
    __syncthreads();
    __shared__ int is_last;
    if (t == 0) {
        atomicAdd(&accum[0], redP[0] + redP[1] + redP[2] + redP[3]);
        atomicAdd(&accum[1], redQ[0] + redQ[1] + redQ[2] + redQ[3]);
        __threadfence();
        unsigned old = atomicAdd((unsigned int*)&accum[3], 1u);
        is_last = (old == gridDim.x * gridDim.y - 1) ? 1 : 0;
    }
    __syncthreads();
    if (is_last) {
        // all other blocks have published their atomics; read via device-scope RMW
        float term = 0.f;
        for (int h = t; h < Hn; h += 256) {
            float v1 = atomicAdd(&cs[h], 0.0f);
            float v2 = atomicAdd(&cs2[h], 0.0f);
            float v3 = atomicAdd(&siv[h], 0.0f);
            float v4 = atomicAdd(&sivmu[h], 0.0f);
            term += v3 * v2 - 2.0f * v4 * v1;
        }
        for (int off = 32; off > 0; off >>= 1) term += __shfl_down(term, off);
        __shared__ float redT[4];
        if (lane == 0) redT[w] = term;
        __syncthreads();
        if (t == 0) {
            float T = redT[0] + redT[1] + redT[2] + redT[3];
            float P = atomicAdd(&accum[0], 0.0f);
            float Q = atomicAdd(&accum[1], 0.0f);
            float pos_sum = -0.5f * P;
            float neg_sum = -0.5f * (T * invB + Q);
            outp[0] = pos_sum * invB;
            outp[1] = (pos_sum - neg_sum) * invB;
        }
    }
}

extern "C" void kernel_launch(void* const* d_in, const int* in_sizes, int n_in,
                              void* d_out, int out_size, void* d_ws, size_t ws_size,
                              hipStream_t stream) {
    const float* modal_a = (const float*)d_in[0];
    const float* modal_b = (const float*)d_in[1];
    const float* W1m = (const float*)d_in[2];
    const float* b1m = (const float*)d_in[3];
    const float* W2m = (const float*)d_in[4];
    const float* b2m = (const float*)d_in[5];
    const float* W1v = (const float*)d_in[6];
    const float* b1v = (const float*)d_in[7];
    const float* W2v = (const float*)d_in[8];
    const float* b2v = (const float*)d_in[9];
    float* out = (float*)d_out;

    char* ws = (char*)d_ws;
    constexpr size_t szAH = (size_t)Bn * Hn * 2;   // bf16 [B,H]
    constexpr size_t szW  = (size_t)Hn * Hn * 2;   // bf16 [H,H]
    short* A_bf   = (short*)(ws);
    short* h1m    = (short*)(ws + szAH);
    short* h1v    = (short*)(ws + 2 * szAH);
    short* W1m_bf = (short*)(ws + 3 * szAH);
    short* W2m_bf = (short*)(ws + 3 * szAH + szW);
    short* W1v_bf = (short*)(ws + 3 * szAH + 2 * szW);
    short* W2v_bf = (short*)(ws + 3 * szAH + 3 * szW);
    float* cs     = (float*)(ws + 3 * szAH + 4 * szW);
    float* cs2    = cs + Hn;
    float* siv    = cs + 2 * Hn;
    float* sivmu  = cs + 3 * Hn;
    float* accum  = cs + 4 * Hn;   // [0]=P [1]=Q [2]=pad [3]=ticket

    // 1. fused zero + convert
    prep_kernel<<<1280, 256, 0, stream>>>(modal_a, W1m, W2m, W1v, W2v,
                                          A_bf, W1m_bf, W2m_bf, W1v_bf, W2v_bf,
                                          cs, 4 * Hn + 8);

    // 2. layer-1 z-paired GEMM (R2 engine + fast_tanh + coalesced stores)
    gemm_l1<<<dim3(Bn / 128, Hn / 128, 2), 256, 0, stream>>>(
        A_bf, W1m_bf, W1v_bf, b1m, b1v, h1m, h1v);

    // 3. layer-2 branch-paired GEMM (128x64, 768 blocks) + CLUB epilogue + in-kernel finalize
    gemm_l2<<<dim3(Bn / 128, Hn / 64), 256, 0, stream>>>(
        h1m, h1v, W2m_bf, W2v_bf, b2m, b2v, modal_b,
        cs, cs2, siv, sivmu, accum, out);
}